// Round 12
// baseline (225.184 us; speedup 1.0000x reference)
//
#include <hip/hip_runtime.h>
#include <hip/hip_bf16.h>
#include <cstddef>
#include <cstdint>

// Problem constants: B=2, C=128, N=32768, K=9, H=512
#define BB 2
#define CC 128
#define NN 32768
#define KNBR 9
#define HH 512
#define PP (BB * NN)          // 65536 points
#define TWO_C 256
#define EPSBN 1e-5f

typedef __attribute__((ext_vector_type(4))) float f32x4;
typedef __attribute__((ext_vector_type(8))) short s16x8;

__device__ __forceinline__ float bf2f(unsigned int u) {
    return __uint_as_float(u << 16);
}
__device__ __forceinline__ unsigned short f2bf(float f) {
    unsigned int u = __float_as_uint(f);
    u += 0x7fffu + ((u >> 16) & 1u);   // RNE
    return (unsigned short)(u >> 16);
}

// per-channel BN+ReLU on a bf16x8 fragment, act params in 4 f32x4 regs
__device__ __forceinline__ s16x8 bnrelu(s16x8 v, f32x4 sa0, f32x4 sa1,
                                        f32x4 sb0, f32x4 sb1) {
    union { s16x8 s; __hip_bfloat162 h[4]; } u;
    u.s = v;
#pragma unroll
    for (int q = 0; q < 4; q++) {
        const float2 f = __bfloat1622float2(u.h[q]);
        const float slo = (q < 2) ? sa0[2 * q] : sa1[2 * q - 4];
        const float shi = (q < 2) ? sa0[2 * q + 1] : sa1[2 * q - 3];
        const float tlo = (q < 2) ? sb0[2 * q] : sb1[2 * q - 4];
        const float thi = (q < 2) ? sb0[2 * q + 1] : sb1[2 * q - 3];
        u.h[q] = __float22bfloat162_rn(make_float2(
            fmaxf(fmaf(slo, f.x, tlo), 0.f), fmaxf(fmaf(shi, f.y, thi), 0.f)));
    }
    return u.s;
}

// Fragment-linear layout for a [P][K] bf16 tensor:
//   F[p/16][k/32][lane][8],  lane = ((k>>3)&3)*16 + (p&15),  elem j = k&7

// ---------------------------------------------------------------------------
// Merged: x [B,C,N] fp32 -> xT [B*N,C] bf16 transpose  +  weight conversion.
__global__ __launch_bounds__(256) void transpose_wconv_kernel(
    const float* __restrict__ x, unsigned short* __restrict__ xT,
    const float* __restrict__ w_mr, const float* __restrict__ w1,
    const float* __restrict__ w2, unsigned short* __restrict__ o_mr,
    unsigned short* __restrict__ o1, unsigned short* __restrict__ o2) {
    if (blockIdx.x >= NN / 32) {
        if (blockIdx.y != 0) return;
        const int t = (blockIdx.x - NN / 32) * 256 + threadIdx.x;  // 0..20479
        const float* src; unsigned short* dst; int K; int slot;
        if (t < 8192) { src = w1; dst = o1; K = 128; slot = t; }
        else if (t < 16384) { src = w2; dst = o2; K = 512; slot = t - 8192; }
        else if (t < 20480) { src = w_mr; dst = o_mr; K = 256; slot = t - 16384; }
        else return;
        const int lane = slot & 63;
        const int kt = (slot >> 6) % (K / 32);
        const int ot = (slot >> 6) / (K / 32);
        const int oc = ot * 16 + (lane & 15);
        const int k0 = kt * 32 + (lane >> 4) * 8;
        s16x8 v;
#pragma unroll
        for (int j = 0; j < 8; j++) v[j] = (short)f2bf(src[(size_t)oc * K + k0 + j]);
        *(s16x8*)(dst + (size_t)slot * 8) = v;
        return;
    }
    __shared__ float t[32][129];
    const int b = blockIdx.y;
    const int n0 = blockIdx.x * 32;
    const int tid = threadIdx.x;
    {
        const int tn = tid % 32;
        const int cq = tid / 32;
        for (int c = cq; c < CC; c += 8)
            t[tn][c] = x[((size_t)b * CC + c) * NN + n0 + tn];
    }
    __syncthreads();
    {
        const int ct = tid % 128;
        const int nq = tid / 128;
        for (int nl = nq; nl < 32; nl += 2)
            xT[((size_t)b * NN + n0 + nl) * CC + ct] = f2bf(t[nl][ct]);
    }
}

// ---------------------------------------------------------------------------
// FUSED gather + GEMM1. Block owns 64 points (4 ptiles).
// Phase 1 (x4): proven 16-point gather (full-row wave reads, padded LDS
// scratch) with the re-layout pass writing DIRECTLY into ALDS fragment
// layout (skips the 64MB featF round-trip).
// Phase 2: proven barrier-free W-stream GEMM mainloop + partials epilogue.
__global__ __launch_bounds__(256, 2) void ggemm1_kernel(
    const unsigned short* __restrict__ xT, const int* __restrict__ ei,
    const unsigned short* __restrict__ W,   // wmrF frag [8][8][64][8]
    const float* __restrict__ bias,
    unsigned short* __restrict__ Cout,      // yF frag [P/16][4][64][8]
    float* __restrict__ part) {             // [gx][2][128]
    constexpr int KT = TWO_C / 32;  // 8 K-steps
    constexpr int NTW = 4;          // n-tiles per wave (OCB=128)
    constexpr int OCT32 = CC / 32;  // 4

    __shared__ __align__(16) unsigned short ALDS[4 * KT * 512];  // 32 KB
    __shared__ __align__(16) unsigned short scr[16 * 264];       // 8.4 KB
    __shared__ float bs[4 * CC];

    const int tid = threadIdx.x;
    const int w = tid >> 6, lane = tid & 63;
    const int mw = w >> 1, nw = w & 1;
    const int lm = lane & 15, lg = lane >> 4;
    const int p0 = blockIdx.x * 64;
    const int b = p0 >> 15;
    const int n0 = p0 & (NN - 1);
    const int pt0 = blockIdx.x * 4;
    const unsigned short* xb = xT + (size_t)b * NN * CC;

    // ---- phase 1: gather 64 points into ALDS fragment layout ----
    for (int it = 0; it < 4; it++) {
#pragma unroll
        for (int q = 0; q < 4; q++) {
            const int spl = w * 4 + q;            // 0..15 within iteration
            const int n = n0 + it * 16 + spl;
            const int* e0 = ei + ((size_t)b * NN + n) * KNBR;         // x_j
            const int* e1 = ei + ((size_t)(BB + b) * NN + n) * KNBR;  // x_i
            const unsigned int xv = *(const unsigned int*)(xb + (size_t)n * CC + lane * 2);
            float m0 = -INFINITY, m1 = -INFINITY;
#pragma unroll
            for (int k = 0; k < KNBR; k++) {
                const int j0 = e0[k], j1 = e1[k];
                const unsigned int va = *(const unsigned int*)(xb + (size_t)j0 * CC + lane * 2);
                const unsigned int vb = *(const unsigned int*)(xb + (size_t)j1 * CC + lane * 2);
                m0 = fmaxf(m0, bf2f(va & 0xffffu) - bf2f(vb & 0xffffu));
                m1 = fmaxf(m1, bf2f(va >> 16) - bf2f(vb >> 16));
            }
            ushort4 o;
            o.x = (unsigned short)(xv & 0xffffu);
            o.y = f2bf(m0);
            o.z = (unsigned short)(xv >> 16);
            o.w = f2bf(m1);
            *(ushort4*)(scr + spl * 264 + lane * 4) = o;
        }
        __syncthreads();
#pragma unroll
        for (int pass = 0; pass < 2; pass++) {
            const int s = pass * 256 + tid;
            const int kt = s >> 6, ln = s & 63;
            const int spl = ln & 15, kq = ln >> 4;
            const s16x8 v = *(const s16x8*)(scr + spl * 264 + kt * 32 + kq * 8);
            *(s16x8*)(ALDS + (size_t)((it * KT + kt) * 64 + ln) * 8) = v;
        }
        __syncthreads();
    }

    // ---- phase 2: GEMM mainloop (barrier-free W stream) ----
    f32x4 acc[2][NTW] = {};
#pragma unroll
    for (int kt = 0; kt < KT; kt++) {
        s16x8 bF[NTW];
#pragma unroll
        for (int n = 0; n < NTW; n++)
            bF[n] = *(const s16x8*)(
                W + ((size_t)((nw * NTW + n) * KT + kt) * 64 + lane) * 8);
        const s16x8 a0 = *(const s16x8*)(ALDS + (size_t)(((mw * 2 + 0) * KT + kt) * 64 + lane) * 8);
        const s16x8 a1 = *(const s16x8*)(ALDS + (size_t)(((mw * 2 + 1) * KT + kt) * 64 + lane) * 8);
#pragma unroll
        for (int n = 0; n < NTW; n++) {
            acc[0][n] = __builtin_amdgcn_mfma_f32_16x16x32_bf16(a0, bF[n], acc[0][n], 0, 0, 0);
            acc[1][n] = __builtin_amdgcn_mfma_f32_16x16x32_bf16(a1, bF[n], acc[1][n], 0, 0, 0);
        }
    }
    __syncthreads();   // ALDS -> epilogue bounce

    // ---- epilogue: bias, stats partials, LDS bounce, frag stores ----
    unsigned short* myct = ALDS + (size_t)w * (NTW / 2) * 512;
    float sA[NTW], sB[NTW], bo[NTW];
#pragma unroll
    for (int n = 0; n < NTW; n++) {
        sA[n] = 0.f; sB[n] = 0.f;
        bo[n] = bias[nw * 64 + n * 16 + lm];
    }
#pragma unroll
    for (int mi = 0; mi < 2; mi++) {
        const int ptile = pt0 + mw * 2 + mi;
#pragma unroll
        for (int n = 0; n < NTW; n++) {
            const int lbase = ((n & 1) * 2 + (lm >> 3)) * 16 + lg * 4;
            const int elem = lm & 7;
#pragma unroll
            for (int j = 0; j < 4; j++) {
                const float h = acc[mi][n][j] + bo[n];
                sA[n] += h;
                sB[n] = fmaf(h, h, sB[n]);
                myct[(size_t)((n >> 1) * 64 + lbase + j) * 8 + elem] = f2bf(h);
            }
        }
#pragma unroll
        for (int og = 0; og < NTW / 2; og++) {
            const s16x8 v = *(const s16x8*)(myct + (size_t)(og * 64 + lane) * 8);
            const int oct = (nw * 64 >> 5) + og;
            *(s16x8*)(Cout + ((size_t)(ptile * OCT32 + oct) * 64 + lane) * 8) = v;
        }
    }
#pragma unroll
    for (int n = 0; n < NTW; n++) {
        float a = sA[n], q = sB[n];
        a += __shfl_xor(a, 16); a += __shfl_xor(a, 32);
        q += __shfl_xor(q, 16); q += __shfl_xor(q, 32);
        if (lg == 0) {
            const int chl = nw * 64 + n * 16 + lm;
            bs[(mw * 2 + 0) * CC + chl] = a;
            bs[(mw * 2 + 1) * CC + chl] = q;
        }
    }
    __syncthreads();
    if (tid < CC) {
        const float s = bs[0 * CC + tid] + bs[2 * CC + tid];
        const float q = bs[1 * CC + tid] + bs[3 * CC + tid];
        const size_t o = (size_t)blockIdx.x * 2 * CC;
        part[o + tid] = s;
        part[o + CC + tid] = q;
    }
}

// ---------------------------------------------------------------------------
// Strip GEMM v3 (R11, proven): A staged+activated once; barrier-free W
// stream; per-block stats partials (no atomics).
template <int KTOT, int OCB, int OC, bool ACT>
__global__ __launch_bounds__(256, 2) void sgemm2_kernel(
    const unsigned short* __restrict__ A,   // frag [P/16][KT][64][8]
    const unsigned short* __restrict__ W,   // frag [OC/16][KT][64][8]
    const float* __restrict__ bias,
    const float* __restrict__ act,          // [2*KTOT]: a then b (if ACT)
    unsigned short* __restrict__ Cout,      // frag [P/16][OC/32][64][8]
    float* __restrict__ part) {             // [by*gx+bx][2][OCB]
    constexpr int KT = KTOT / 32;   // K-steps
    constexpr int NTB = OCB / 16;   // n-tiles per block slice
    constexpr int NTW = NTB / 2;    // n-tiles per wave
    constexpr int OCT32 = OC / 32;

    __shared__ __align__(16) unsigned short ALDS[4 * KT * 512];
    __shared__ float bs[4 * OCB];

    const int tid = threadIdx.x;
    const int w = tid >> 6, lane = tid & 63;
    const int mw = w >> 1, nw = w & 1;
    const int lm = lane & 15, lg = lane >> 4;
    const int pt0 = blockIdx.x * 4;           // first ptile of this block
    const int ob = blockIdx.y * OCB;

    // ---- prologue: stage A-tile (full K), BN+ReLU applied in-flight ----
    {
        const unsigned short* Asrc = A + (size_t)pt0 * KT * 512;
        s16x8 ar[KT];
#pragma unroll
        for (int i = 0; i < KT; i++)
            ar[i] = *(const s16x8*)(Asrc + (size_t)(i * 256 + tid) * 8);
        if (ACT) {
#pragma unroll
            for (int i = 0; i < KT; i++) {
                const int s = i * 256 + tid;
                const int kts = (s >> 6) % KT;
                const int lgs = (s & 63) >> 4;
                const int ke = kts * 32 + lgs * 8;
                const f32x4 xa0 = *(const f32x4*)(act + ke);
                const f32x4 xa1 = *(const f32x4*)(act + ke + 4);
                const f32x4 xb0 = *(const f32x4*)(act + KTOT + ke);
                const f32x4 xb1 = *(const f32x4*)(act + KTOT + ke + 4);
                ar[i] = bnrelu(ar[i], xa0, xa1, xb0, xb1);
            }
        }
#pragma unroll
        for (int i = 0; i < KT; i++)
            *(s16x8*)(ALDS + (size_t)(i * 256 + tid) * 8) = ar[i];
    }
    __syncthreads();

    f32x4 acc[2][NTW] = {};

#pragma unroll
    for (int kt = 0; kt < KT; kt++) {
        s16x8 bF[NTW];
#pragma unroll
        for (int n = 0; n < NTW; n++)
            bF[n] = *(const s16x8*)(
                W + ((size_t)(((ob >> 4) + nw * NTW + n) * KT + kt) * 64 + lane) * 8);
        const s16x8 a0 = *(const s16x8*)(ALDS + (size_t)(((mw * 2 + 0) * KT + kt) * 64 + lane) * 8);
        const s16x8 a1 = *(const s16x8*)(ALDS + (size_t)(((mw * 2 + 1) * KT + kt) * 64 + lane) * 8);
#pragma unroll
        for (int n = 0; n < NTW; n++) {
            acc[0][n] = __builtin_amdgcn_mfma_f32_16x16x32_bf16(a0, bF[n], acc[0][n], 0, 0, 0);
            acc[1][n] = __builtin_amdgcn_mfma_f32_16x16x32_bf16(a1, bF[n], acc[1][n], 0, 0, 0);
        }
    }
    __syncthreads();   // all waves done reading A -> ALDS reusable as bounce

    // ---- epilogue: bias, stats, bounce via ALDS (wave-private), stores ----
    unsigned short* myct = ALDS + (size_t)w * (NTW / 2) * 512;
    float sA[NTW], sB[NTW], bo[NTW];
#pragma unroll
    for (int n = 0; n < NTW; n++) {
        sA[n] = 0.f; sB[n] = 0.f;
        bo[n] = bias[ob + nw * (OCB / 2) + n * 16 + lm];
    }
#pragma unroll
    for (int mi = 0; mi < 2; mi++) {
        const int ptile = pt0 + mw * 2 + mi;
#pragma unroll
        for (int n = 0; n < NTW; n++) {
            const int lbase = ((n & 1) * 2 + (lm >> 3)) * 16 + lg * 4;
            const int elem = lm & 7;
#pragma unroll
            for (int j = 0; j < 4; j++) {
                const float h = acc[mi][n][j] + bo[n];
                sA[n] += h;
                sB[n] = fmaf(h, h, sB[n]);
                myct[(size_t)((n >> 1) * 64 + lbase + j) * 8 + elem] = f2bf(h);
            }
        }
#pragma unroll
        for (int og = 0; og < NTW / 2; og++) {
            const s16x8 v = *(const s16x8*)(myct + (size_t)(og * 64 + lane) * 8);
            const int oct = ((ob + nw * (OCB / 2)) >> 5) + og;
            *(s16x8*)(Cout + ((size_t)(ptile * OCT32 + oct) * 64 + lane) * 8) = v;
        }
    }
#pragma unroll
    for (int n = 0; n < NTW; n++) {
        float a = sA[n], q = sB[n];
        a += __shfl_xor(a, 16); a += __shfl_xor(a, 32);
        q += __shfl_xor(q, 16); q += __shfl_xor(q, 32);
        if (lg == 0) {
            const int chl = nw * (OCB / 2) + n * 16 + lm;
            bs[(mw * 2 + 0) * OCB + chl] = a;
            bs[(mw * 2 + 1) * OCB + chl] = q;
        }
    }
    __syncthreads();
    if (tid < OCB) {
        const float s = bs[0 * OCB + tid] + bs[2 * OCB + tid];
        const float q = bs[1 * OCB + tid] + bs[3 * OCB + tid];
        const size_t o = ((size_t)blockIdx.y * gridDim.x + blockIdx.x) * 2 * OCB;
        part[o + tid] = s;
        part[o + OCB + tid] = q;
    }
}

// ---------------------------------------------------------------------------
// PARALLEL partial-reduce: one block per CHANNEL (grid = OC).
template <int OCB, int GX>
__global__ __launch_bounds__(256) void reduce_kernel(
    const float* __restrict__ part, const float* __restrict__ g,
    const float* __restrict__ be, float* __restrict__ act, int OC, float invP) {
    __shared__ float ls[4], lq[4];
    const int c = blockIdx.x;
    const int by = c / OCB, co = c % OCB;
    const int tid = threadIdx.x;
    float s = 0.f, q = 0.f;
#pragma unroll
    for (int i = 0; i < GX / 256; i++) {
        const int bx = i * 256 + tid;
        const size_t o = (size_t)(by * GX + bx) * 2 * OCB;
        s += part[o + co];
        q += part[o + OCB + co];
    }
#pragma unroll
    for (int off = 32; off >= 1; off >>= 1) {
        s += __shfl_xor(s, off);
        q += __shfl_xor(q, off);
    }
    if ((tid & 63) == 0) { ls[tid >> 6] = s; lq[tid >> 6] = q; }
    __syncthreads();
    if (tid == 0) {
        s = ls[0] + ls[1] + ls[2] + ls[3];
        q = lq[0] + lq[1] + lq[2] + lq[3];
        const float mean = s * invP;
        const float var = q * invP - mean * mean;
        const float a = g[c] * rsqrtf(var + EPSBN);
        act[c] = a;
        act[OC + c] = be[c] - mean * a;
    }
}

// ---------------------------------------------------------------------------
// out[b,c,n] = a3*o + b3 + relu(a1*y + b1); frag tiles -> [B,C,N] via LDS.
__global__ __launch_bounds__(256) void final_kernel(
    const unsigned short* __restrict__ yF, const unsigned short* __restrict__ oF,
    const float* __restrict__ act1, const float* __restrict__ act3,
    float* __restrict__ out) {
    __shared__ float t[32][132];
    const int p0 = blockIdx.x * 32;
    const int b = p0 >> 15;
    const int n0 = p0 & (NN - 1);
    const int tid = threadIdx.x;
#pragma unroll
    for (int s = tid; s < 512; s += 256) {
        const int pt = s >> 8;
        const int kt = (s >> 6) & 3;
        const int lane = s & 63;
        const int nl = pt * 16 + (lane & 15);
        const int c0 = kt * 32 + (lane >> 4) * 8;
        const size_t off = ((size_t)(((p0 >> 4) + pt) * 4 + kt) * 64 + lane) * 8;
        const s16x8 yv = *(const s16x8*)(yF + off);
        const s16x8 ov = *(const s16x8*)(oF + off);
        const f32x4 a1lo = *(const f32x4*)(act1 + c0);
        const f32x4 a1hi = *(const f32x4*)(act1 + c0 + 4);
        const f32x4 b1lo = *(const f32x4*)(act1 + CC + c0);
        const f32x4 b1hi = *(const f32x4*)(act1 + CC + c0 + 4);
        const f32x4 a3lo = *(const f32x4*)(act3 + c0);
        const f32x4 a3hi = *(const f32x4*)(act3 + c0 + 4);
        const f32x4 b3lo = *(const f32x4*)(act3 + CC + c0);
        const f32x4 b3hi = *(const f32x4*)(act3 + CC + c0 + 4);
#pragma unroll
        for (int j = 0; j < 8; j++) {
            const float yf = bf2f((unsigned short)yv[j]);
            const float of = bf2f((unsigned short)ov[j]);
            const float a1 = (j < 4) ? a1lo[j] : a1hi[j - 4];
            const float b1 = (j < 4) ? b1lo[j] : b1hi[j - 4];
            const float a3 = (j < 4) ? a3lo[j] : a3hi[j - 4];
            const float b3 = (j < 4) ? b3lo[j] : b3hi[j - 4];
            t[nl][c0 + j] = fmaf(a3, of, b3) + fmaxf(fmaf(a1, yf, b1), 0.f);
        }
    }
    __syncthreads();
    const int tn = tid & 31;
    const int cq = tid >> 5;
    for (int c = cq; c < CC; c += 8)
        out[((size_t)b * CC + c) * NN + n0 + tn] = t[tn][c];
}

// ---------------------------------------------------------------------------
extern "C" void kernel_launch(void* const* d_in, const int* in_sizes, int n_in,
                              void* d_out, int out_size, void* d_ws, size_t ws_size,
                              hipStream_t stream) {
    const float* x     = (const float*)d_in[0];
    const int*   ei    = (const int*)d_in[1];
    const float* w_mr  = (const float*)d_in[2];
    const float* b_mr  = (const float*)d_in[3];
    const float* g_mr  = (const float*)d_in[4];
    const float* be_mr = (const float*)d_in[5];
    const float* w1    = (const float*)d_in[6];
    const float* b1    = (const float*)d_in[7];
    const float* g1    = (const float*)d_in[8];
    const float* be1   = (const float*)d_in[9];
    const float* w2    = (const float*)d_in[10];
    const float* b2    = (const float*)d_in[11];
    const float* g2    = (const float*)d_in[12];
    const float* be2   = (const float*)d_in[13];
    float* out = (float*)d_out;

    // workspace layout (bytes); partials live in regions dead at their time.
    char* ws = (char*)d_ws;
    unsigned short* xT    = (unsigned short*)(ws + 0);           // 16 MB
    unsigned short* yF    = (unsigned short*)(ws + 50331648);    // 16 MB frag
    unsigned short* hF    = (unsigned short*)(ws + 67108864);    // 64 MB frag
    unsigned short* oF    = (unsigned short*)(ws + 134217728);   // 16 MB frag
    unsigned short* wmrF  = (unsigned short*)(ws + 150994944);   // 64 KB frag
    unsigned short* w1F   = (unsigned short*)(ws + 151060480);   // 128 KB frag
    unsigned short* w2F   = (unsigned short*)(ws + 151191552);   // 128 KB frag
    float* act1  = (float*)(ws + 151322624);                     // 2*128
    float* act2  = (float*)(ws + 151323648);                     // 2*512
    float* act3  = (float*)(ws + 151327744);                     // 2*128
    float* part1 = (float*)(ws + 67108864);                      // 1 MB (in hF)
    float* part2 = (float*)(ws + 134217728);                     // 4 MB (in oF)
    float* part3 = (float*)(ws + 16777216);                      // 1 MB (old featF)

    const float invP = 1.0f / (float)PP;

    transpose_wconv_kernel<<<dim3(NN / 32 + 80, BB), 256, 0, stream>>>(
        x, xT, w_mr, w1, w2, wmrF, w1F, w2F);

    // FUSED gather + GEMM1: x/edges -> y[P,128]  (no featF round-trip)
    ggemm1_kernel<<<PP / 64, 256, 0, stream>>>(xT, ei, wmrF, b_mr, yF, part1);
    reduce_kernel<CC, PP / 64><<<CC, 256, 0, stream>>>(
        part1, g_mr, be_mr, act1, CC, invP);

    // GEMM2: relu(bn1(y))[P,128] @ w1^T -> h[P,512]   (grid.y=2: 256-ch slices)
    sgemm2_kernel<CC, 256, HH, true><<<dim3(PP / 64, 2), 256, 0, stream>>>(
        yF, w1F, b1, act1, hF, part2);
    reduce_kernel<256, PP / 64><<<HH, 256, 0, stream>>>(
        part2, g1, be1, act2, HH, invP);

    // GEMM3: relu(bn2(h))[P,512] @ w2^T -> o[P,128]
    sgemm2_kernel<HH, CC, CC, true><<<dim3(PP / 64, 1), 256, 0, stream>>>(
        hF, w2F, b2, act2, oF, part3);
    reduce_kernel<CC, PP / 64><<<CC, 256, 0, stream>>>(
        part3, g2, be2, act3, CC, invP);

    // out = bn3(o) + relu(bn1(y)), back to [B,C,N]
    final_kernel<<<PP / 32, 256, 0, stream>>>(yF, oF, act1, act3, out);
}

// Round 13
// 143.244 us; speedup vs baseline: 1.5720x; 1.5720x over previous
//
#include <hip/hip_runtime.h>
#include <hip/hip_bf16.h>
#include <cstddef>
#include <cstdint>

// Problem constants: B=2, C=128, N=32768, K=9, H=512
#define BB 2
#define CC 128
#define NN 32768
#define KNBR 9
#define HH 512
#define PP (BB * NN)          // 65536 points
#define TWO_C 256
#define EPSBN 1e-5f

typedef __attribute__((ext_vector_type(4))) float f32x4;
typedef __attribute__((ext_vector_type(8))) short s16x8;

__device__ __forceinline__ float bf2f(unsigned int u) {
    return __uint_as_float(u << 16);
}
__device__ __forceinline__ unsigned short f2bf(float f) {
    unsigned int u = __float_as_uint(f);
    u += 0x7fffu + ((u >> 16) & 1u);   // RNE
    return (unsigned short)(u >> 16);
}

// per-channel BN+ReLU on a bf16x8 fragment, act params in 4 f32x4 regs
__device__ __forceinline__ s16x8 bnrelu(s16x8 v, f32x4 sa0, f32x4 sa1,
                                        f32x4 sb0, f32x4 sb1) {
    union { s16x8 s; __hip_bfloat162 h[4]; } u;
    u.s = v;
#pragma unroll
    for (int q = 0; q < 4; q++) {
        const float2 f = __bfloat1622float2(u.h[q]);
        const float slo = (q < 2) ? sa0[2 * q] : sa1[2 * q - 4];
        const float shi = (q < 2) ? sa0[2 * q + 1] : sa1[2 * q - 3];
        const float tlo = (q < 2) ? sb0[2 * q] : sb1[2 * q - 4];
        const float thi = (q < 2) ? sb0[2 * q + 1] : sb1[2 * q - 3];
        u.h[q] = __float22bfloat162_rn(make_float2(
            fmaxf(fmaf(slo, f.x, tlo), 0.f), fmaxf(fmaf(shi, f.y, thi), 0.f)));
    }
    return u.s;
}

// Fragment-linear layout for a [P][K] bf16 tensor:
//   F[p/16][k/32][lane][8],  lane = ((k>>3)&3)*16 + (p&15),  elem j = k&7

// ---------------------------------------------------------------------------
// Merged: x [B,C,N] fp32 -> xT [B*N,C] bf16 transpose  +  weight conversion.
__global__ __launch_bounds__(256) void transpose_wconv_kernel(
    const float* __restrict__ x, unsigned short* __restrict__ xT,
    const float* __restrict__ w_mr, const float* __restrict__ w1,
    const float* __restrict__ w2, unsigned short* __restrict__ o_mr,
    unsigned short* __restrict__ o1, unsigned short* __restrict__ o2) {
    if (blockIdx.x >= NN / 32) {
        if (blockIdx.y != 0) return;
        const int t = (blockIdx.x - NN / 32) * 256 + threadIdx.x;  // 0..20479
        const float* src; unsigned short* dst; int K; int slot;
        if (t < 8192) { src = w1; dst = o1; K = 128; slot = t; }
        else if (t < 16384) { src = w2; dst = o2; K = 512; slot = t - 8192; }
        else if (t < 20480) { src = w_mr; dst = o_mr; K = 256; slot = t - 16384; }
        else return;
        const int lane = slot & 63;
        const int kt = (slot >> 6) % (K / 32);
        const int ot = (slot >> 6) / (K / 32);
        const int oc = ot * 16 + (lane & 15);
        const int k0 = kt * 32 + (lane >> 4) * 8;
        s16x8 v;
#pragma unroll
        for (int j = 0; j < 8; j++) v[j] = (short)f2bf(src[(size_t)oc * K + k0 + j]);
        *(s16x8*)(dst + (size_t)slot * 8) = v;
        return;
    }
    __shared__ float t[32][129];
    const int b = blockIdx.y;
    const int n0 = blockIdx.x * 32;
    const int tid = threadIdx.x;
    {
        const int tn = tid % 32;
        const int cq = tid / 32;
        for (int c = cq; c < CC; c += 8)
            t[tn][c] = x[((size_t)b * CC + c) * NN + n0 + tn];
    }
    __syncthreads();
    {
        const int ct = tid % 128;
        const int nq = tid / 128;
        for (int nl = nq; nl < 32; nl += 2)
            xT[((size_t)b * NN + n0 + nl) * CC + ct] = f2bf(t[nl][ct]);
    }
}

// ---------------------------------------------------------------------------
// Gather + max-relative -> feat in fragment layout (R5 structure, proven).
__global__ __launch_bounds__(256) void gather_kernel(
    const unsigned short* __restrict__ xT, const int* __restrict__ ei,
    unsigned short* __restrict__ feat) {
    __shared__ unsigned short lds[16 * 264];   // 16 points x 256 k, +8 pad
    const int p0 = blockIdx.x * 16;
    const int b = p0 >> 15;
    const int n0 = p0 & (NN - 1);
    const int tid = threadIdx.x;
    const int wv = tid >> 6, lane = tid & 63;
    const unsigned short* xb = xT + (size_t)b * NN * CC;

#pragma unroll
    for (int q = 0; q < 4; q++) {
        const int pl = wv * 4 + q;
        const int n = n0 + pl;
        const int* e0 = ei + ((size_t)b * NN + n) * KNBR;         // x_j
        const int* e1 = ei + ((size_t)(BB + b) * NN + n) * KNBR;  // x_i
        const unsigned int xv = *(const unsigned int*)(xb + (size_t)n * CC + lane * 2);
        float m0 = -INFINITY, m1 = -INFINITY;
#pragma unroll
        for (int k = 0; k < KNBR; k++) {
            const int j0 = e0[k], j1 = e1[k];
            const unsigned int va = *(const unsigned int*)(xb + (size_t)j0 * CC + lane * 2);
            const unsigned int vb = *(const unsigned int*)(xb + (size_t)j1 * CC + lane * 2);
            m0 = fmaxf(m0, bf2f(va & 0xffffu) - bf2f(vb & 0xffffu));
            m1 = fmaxf(m1, bf2f(va >> 16) - bf2f(vb >> 16));
        }
        ushort4 o;
        o.x = (unsigned short)(xv & 0xffffu);
        o.y = f2bf(m0);
        o.z = (unsigned short)(xv >> 16);
        o.w = f2bf(m1);
        *(ushort4*)(lds + pl * 264 + lane * 4) = o;
    }
    __syncthreads();
#pragma unroll
    for (int pass = 0; pass < 2; pass++) {
        const int s = pass * 256 + tid;
        const int kt = s >> 6, ln = s & 63;
        const int pl = ln & 15, kq = ln >> 4;
        const s16x8 v = *(const s16x8*)(lds + pl * 264 + kt * 32 + kq * 8);
        *(s16x8*)(feat + ((size_t)((p0 >> 4) * 8 + kt) * 64 + ln) * 8) = v;
    }
}

// ---------------------------------------------------------------------------
// Strip GEMM v3 (R11, proven): A staged+activated once; barrier-free W
// stream; per-block stats partials (no atomics).
template <int KTOT, int OCB, int OC, bool ACT>
__global__ __launch_bounds__(256, 2) void sgemm2_kernel(
    const unsigned short* __restrict__ A,   // frag [P/16][KT][64][8]
    const unsigned short* __restrict__ W,   // frag [OC/16][KT][64][8]
    const float* __restrict__ bias,
    const float* __restrict__ act,          // [2*KTOT]: a then b (if ACT)
    unsigned short* __restrict__ Cout,      // frag [P/16][OC/32][64][8]
    float* __restrict__ part) {             // [by*gx+bx][2][OCB]
    constexpr int KT = KTOT / 32;   // K-steps
    constexpr int NTB = OCB / 16;   // n-tiles per block slice
    constexpr int NTW = NTB / 2;    // n-tiles per wave
    constexpr int OCT32 = OC / 32;

    __shared__ __align__(16) unsigned short ALDS[4 * KT * 512];
    __shared__ float bs[4 * OCB];

    const int tid = threadIdx.x;
    const int w = tid >> 6, lane = tid & 63;
    const int mw = w >> 1, nw = w & 1;
    const int lm = lane & 15, lg = lane >> 4;
    const int pt0 = blockIdx.x * 4;           // first ptile of this block
    const int ob = blockIdx.y * OCB;

    // ---- prologue: stage A-tile (full K), BN+ReLU applied in-flight ----
    {
        const unsigned short* Asrc = A + (size_t)pt0 * KT * 512;
        s16x8 ar[KT];
#pragma unroll
        for (int i = 0; i < KT; i++)
            ar[i] = *(const s16x8*)(Asrc + (size_t)(i * 256 + tid) * 8);
        if (ACT) {
#pragma unroll
            for (int i = 0; i < KT; i++) {
                const int s = i * 256 + tid;
                const int kts = (s >> 6) % KT;
                const int lgs = (s & 63) >> 4;
                const int ke = kts * 32 + lgs * 8;
                const f32x4 xa0 = *(const f32x4*)(act + ke);
                const f32x4 xa1 = *(const f32x4*)(act + ke + 4);
                const f32x4 xb0 = *(const f32x4*)(act + KTOT + ke);
                const f32x4 xb1 = *(const f32x4*)(act + KTOT + ke + 4);
                ar[i] = bnrelu(ar[i], xa0, xa1, xb0, xb1);
            }
        }
#pragma unroll
        for (int i = 0; i < KT; i++)
            *(s16x8*)(ALDS + (size_t)(i * 256 + tid) * 8) = ar[i];
    }
    __syncthreads();

    f32x4 acc[2][NTW] = {};

#pragma unroll
    for (int kt = 0; kt < KT; kt++) {
        s16x8 bF[NTW];
#pragma unroll
        for (int n = 0; n < NTW; n++)
            bF[n] = *(const s16x8*)(
                W + ((size_t)(((ob >> 4) + nw * NTW + n) * KT + kt) * 64 + lane) * 8);
        const s16x8 a0 = *(const s16x8*)(ALDS + (size_t)(((mw * 2 + 0) * KT + kt) * 64 + lane) * 8);
        const s16x8 a1 = *(const s16x8*)(ALDS + (size_t)(((mw * 2 + 1) * KT + kt) * 64 + lane) * 8);
#pragma unroll
        for (int n = 0; n < NTW; n++) {
            acc[0][n] = __builtin_amdgcn_mfma_f32_16x16x32_bf16(a0, bF[n], acc[0][n], 0, 0, 0);
            acc[1][n] = __builtin_amdgcn_mfma_f32_16x16x32_bf16(a1, bF[n], acc[1][n], 0, 0, 0);
        }
    }
    __syncthreads();   // all waves done reading A -> ALDS reusable as bounce

    // ---- epilogue: bias, stats, bounce via ALDS (wave-private), stores ----
    unsigned short* myct = ALDS + (size_t)w * (NTW / 2) * 512;
    float sA[NTW], sB[NTW], bo[NTW];
#pragma unroll
    for (int n = 0; n < NTW; n++) {
        sA[n] = 0.f; sB[n] = 0.f;
        bo[n] = bias[ob + nw * (OCB / 2) + n * 16 + lm];
    }
#pragma unroll
    for (int mi = 0; mi < 2; mi++) {
        const int ptile = pt0 + mw * 2 + mi;
#pragma unroll
        for (int n = 0; n < NTW; n++) {
            const int lbase = ((n & 1) * 2 + (lm >> 3)) * 16 + lg * 4;
            const int elem = lm & 7;
#pragma unroll
            for (int j = 0; j < 4; j++) {
                const float h = acc[mi][n][j] + bo[n];
                sA[n] += h;
                sB[n] = fmaf(h, h, sB[n]);
                myct[(size_t)((n >> 1) * 64 + lbase + j) * 8 + elem] = f2bf(h);
            }
        }
#pragma unroll
        for (int og = 0; og < NTW / 2; og++) {
            const s16x8 v = *(const s16x8*)(myct + (size_t)(og * 64 + lane) * 8);
            const int oct = ((ob + nw * (OCB / 2)) >> 5) + og;
            *(s16x8*)(Cout + ((size_t)(ptile * OCT32 + oct) * 64 + lane) * 8) = v;
        }
    }
#pragma unroll
    for (int n = 0; n < NTW; n++) {
        float a = sA[n], q = sB[n];
        a += __shfl_xor(a, 16); a += __shfl_xor(a, 32);
        q += __shfl_xor(q, 16); q += __shfl_xor(q, 32);
        if (lg == 0) {
            const int chl = nw * (OCB / 2) + n * 16 + lm;
            bs[(mw * 2 + 0) * OCB + chl] = a;
            bs[(mw * 2 + 1) * OCB + chl] = q;
        }
    }
    __syncthreads();
    if (tid < OCB) {
        const float s = bs[0 * OCB + tid] + bs[2 * OCB + tid];
        const float q = bs[1 * OCB + tid] + bs[3 * OCB + tid];
        const size_t o = ((size_t)blockIdx.y * gridDim.x + blockIdx.x) * 2 * OCB;
        part[o + tid] = s;
        part[o + OCB + tid] = q;
    }
}

// ---------------------------------------------------------------------------
// GEMM3 (K=512): K staged in TWO 32KB chunks (T14 issue-early/write-late for
// chunk 1) -> LDS 34KB instead of 66KB -> 4 blocks/CU instead of 2.
// Mainloop/epilogue verbatim from sgemm2. OCB=OC=128, ACT, grid.y=1.
__global__ __launch_bounds__(256, 4) void sgemm3_kernel(
    const unsigned short* __restrict__ A,   // hF frag [P/16][16][64][8]
    const unsigned short* __restrict__ W,   // w2F frag [8][16][64][8]
    const float* __restrict__ bias,
    const float* __restrict__ act,          // [2*512]
    unsigned short* __restrict__ Cout,      // oF frag [P/16][4][64][8]
    float* __restrict__ part) {             // [gx][2][128]
    constexpr int KT = 16, KCH = 8, NTW = 4, OCT32 = CC / 32;

    __shared__ __align__(16) unsigned short ALDS[4 * KCH * 512];  // 32 KB
    __shared__ float bs[4 * CC];

    const int tid = threadIdx.x;
    const int w = tid >> 6, lane = tid & 63;
    const int mw = w >> 1, nw = w & 1;
    const int lm = lane & 15, lg = lane >> 4;
    const int pt0 = blockIdx.x * 4;
    const unsigned short* Asrc = A + (size_t)pt0 * KT * 512;

    // stage chunk 0 (kt 0..7), bnrelu in-flight
    {
        s16x8 ar[KCH];
#pragma unroll
        for (int i = 0; i < KCH; i++) {
            const int s = i * 256 + tid;
            const int tile = s >> 6, ln = s & 63;          // tile = pl*8+kk
            const int pl = tile >> 3, kk = tile & 7;
            ar[i] = *(const s16x8*)(Asrc + (size_t)((pl * KT + kk) * 64 + ln) * 8);
            const int ke = kk * 32 + (ln >> 4) * 8;
            ar[i] = bnrelu(ar[i],
                           *(const f32x4*)(act + ke), *(const f32x4*)(act + ke + 4),
                           *(const f32x4*)(act + HH + ke), *(const f32x4*)(act + HH + ke + 4));
        }
#pragma unroll
        for (int i = 0; i < KCH; i++)
            *(s16x8*)(ALDS + (size_t)(i * 256 + tid) * 8) = ar[i];
    }
    __syncthreads();

    f32x4 acc[2][NTW] = {};

    // issue chunk 1 loads early (T14): global latency hides under chunk-0 MFMAs
    s16x8 arn[KCH];
#pragma unroll
    for (int i = 0; i < KCH; i++) {
        const int s = i * 256 + tid;
        const int tile = s >> 6, ln = s & 63;
        const int pl = tile >> 3, kk = tile & 7;
        arn[i] = *(const s16x8*)(Asrc + (size_t)((pl * KT + 8 + kk) * 64 + ln) * 8);
    }

#pragma unroll
    for (int chunk = 0; chunk < 2; chunk++) {
#pragma unroll
        for (int kk = 0; kk < KCH; kk++) {
            const int kt = chunk * KCH + kk;
            s16x8 bF[NTW];
#pragma unroll
            for (int n = 0; n < NTW; n++)
                bF[n] = *(const s16x8*)(
                    W + ((size_t)((nw * NTW + n) * KT + kt) * 64 + lane) * 8);
            const s16x8 a0 = *(const s16x8*)(ALDS + (size_t)(((mw * 2 + 0) * KCH + kk) * 64 + lane) * 8);
            const s16x8 a1 = *(const s16x8*)(ALDS + (size_t)(((mw * 2 + 1) * KCH + kk) * 64 + lane) * 8);
#pragma unroll
            for (int n = 0; n < NTW; n++) {
                acc[0][n] = __builtin_amdgcn_mfma_f32_16x16x32_bf16(a0, bF[n], acc[0][n], 0, 0, 0);
                acc[1][n] = __builtin_amdgcn_mfma_f32_16x16x32_bf16(a1, bF[n], acc[1][n], 0, 0, 0);
            }
        }
        if (chunk == 0) {
            __syncthreads();   // everyone done reading chunk 0
#pragma unroll
            for (int i = 0; i < KCH; i++) {
                const int s = i * 256 + tid;
                const int tile = s >> 6, ln = s & 63;
                const int kk = tile & 7;
                const int ke = (8 + kk) * 32 + (ln >> 4) * 8;
                arn[i] = bnrelu(arn[i],
                                *(const f32x4*)(act + ke), *(const f32x4*)(act + ke + 4),
                                *(const f32x4*)(act + HH + ke), *(const f32x4*)(act + HH + ke + 4));
                *(s16x8*)(ALDS + (size_t)(i * 256 + tid) * 8) = arn[i];
            }
            __syncthreads();
        }
    }
    __syncthreads();   // ALDS -> epilogue bounce

    // ---- epilogue (verbatim sgemm2, ob=0, OCB=128) ----
    unsigned short* myct = ALDS + (size_t)w * (NTW / 2) * 512;
    float sA[NTW], sB[NTW], bo[NTW];
#pragma unroll
    for (int n = 0; n < NTW; n++) {
        sA[n] = 0.f; sB[n] = 0.f;
        bo[n] = bias[nw * 64 + n * 16 + lm];
    }
#pragma unroll
    for (int mi = 0; mi < 2; mi++) {
        const int ptile = pt0 + mw * 2 + mi;
#pragma unroll
        for (int n = 0; n < NTW; n++) {
            const int lbase = ((n & 1) * 2 + (lm >> 3)) * 16 + lg * 4;
            const int elem = lm & 7;
#pragma unroll
            for (int j = 0; j < 4; j++) {
                const float h = acc[mi][n][j] + bo[n];
                sA[n] += h;
                sB[n] = fmaf(h, h, sB[n]);
                myct[(size_t)((n >> 1) * 64 + lbase + j) * 8 + elem] = f2bf(h);
            }
        }
#pragma unroll
        for (int og = 0; og < NTW / 2; og++) {
            const s16x8 v = *(const s16x8*)(myct + (size_t)(og * 64 + lane) * 8);
            const int oct = (nw * 64 >> 5) + og;
            *(s16x8*)(Cout + ((size_t)(ptile * OCT32 + oct) * 64 + lane) * 8) = v;
        }
    }
#pragma unroll
    for (int n = 0; n < NTW; n++) {
        float a = sA[n], q = sB[n];
        a += __shfl_xor(a, 16); a += __shfl_xor(a, 32);
        q += __shfl_xor(q, 16); q += __shfl_xor(q, 32);
        if (lg == 0) {
            const int chl = nw * 64 + n * 16 + lm;
            bs[(mw * 2 + 0) * CC + chl] = a;
            bs[(mw * 2 + 1) * CC + chl] = q;
        }
    }
    __syncthreads();
    if (tid < CC) {
        const float s = bs[0 * CC + tid] + bs[2 * CC + tid];
        const float q = bs[1 * CC + tid] + bs[3 * CC + tid];
        const size_t o = (size_t)blockIdx.x * 2 * CC;
        part[o + tid] = s;
        part[o + CC + tid] = q;
    }
}

// ---------------------------------------------------------------------------
// PARALLEL partial-reduce: one block per CHANNEL (grid = OC).
template <int OCB, int GX>
__global__ __launch_bounds__(256) void reduce_kernel(
    const float* __restrict__ part, const float* __restrict__ g,
    const float* __restrict__ be, float* __restrict__ act, int OC, float invP) {
    __shared__ float ls[4], lq[4];
    const int c = blockIdx.x;
    const int by = c / OCB, co = c % OCB;
    const int tid = threadIdx.x;
    float s = 0.f, q = 0.f;
#pragma unroll
    for (int i = 0; i < GX / 256; i++) {
        const int bx = i * 256 + tid;
        const size_t o = (size_t)(by * GX + bx) * 2 * OCB;
        s += part[o + co];
        q += part[o + OCB + co];
    }
#pragma unroll
    for (int off = 32; off >= 1; off >>= 1) {
        s += __shfl_xor(s, off);
        q += __shfl_xor(q, off);
    }
    if ((tid & 63) == 0) { ls[tid >> 6] = s; lq[tid >> 6] = q; }
    __syncthreads();
    if (tid == 0) {
        s = ls[0] + ls[1] + ls[2] + ls[3];
        q = lq[0] + lq[1] + lq[2] + lq[3];
        const float mean = s * invP;
        const float var = q * invP - mean * mean;
        const float a = g[c] * rsqrtf(var + EPSBN);
        act[c] = a;
        act[OC + c] = be[c] - mean * a;
    }
}

// ---------------------------------------------------------------------------
// out[b,c,n] = a3*o + b3 + relu(a1*y + b1); frag tiles -> [B,C,N] via LDS.
__global__ __launch_bounds__(256) void final_kernel(
    const unsigned short* __restrict__ yF, const unsigned short* __restrict__ oF,
    const float* __restrict__ act1, const float* __restrict__ act3,
    float* __restrict__ out) {
    __shared__ float t[32][132];
    const int p0 = blockIdx.x * 32;
    const int b = p0 >> 15;
    const int n0 = p0 & (NN - 1);
    const int tid = threadIdx.x;
#pragma unroll
    for (int s = tid; s < 512; s += 256) {
        const int pt = s >> 8;
        const int kt = (s >> 6) & 3;
        const int lane = s & 63;
        const int nl = pt * 16 + (lane & 15);
        const int c0 = kt * 32 + (lane >> 4) * 8;
        const size_t off = ((size_t)(((p0 >> 4) + pt) * 4 + kt) * 64 + lane) * 8;
        const s16x8 yv = *(const s16x8*)(yF + off);
        const s16x8 ov = *(const s16x8*)(oF + off);
        const f32x4 a1lo = *(const f32x4*)(act1 + c0);
        const f32x4 a1hi = *(const f32x4*)(act1 + c0 + 4);
        const f32x4 b1lo = *(const f32x4*)(act1 + CC + c0);
        const f32x4 b1hi = *(const f32x4*)(act1 + CC + c0 + 4);
        const f32x4 a3lo = *(const f32x4*)(act3 + c0);
        const f32x4 a3hi = *(const f32x4*)(act3 + c0 + 4);
        const f32x4 b3lo = *(const f32x4*)(act3 + CC + c0);
        const f32x4 b3hi = *(const f32x4*)(act3 + CC + c0 + 4);
#pragma unroll
        for (int j = 0; j < 8; j++) {
            const float yf = bf2f((unsigned short)yv[j]);
            const float of = bf2f((unsigned short)ov[j]);
            const float a1 = (j < 4) ? a1lo[j] : a1hi[j - 4];
            const float b1 = (j < 4) ? b1lo[j] : b1hi[j - 4];
            const float a3 = (j < 4) ? a3lo[j] : a3hi[j - 4];
            const float b3 = (j < 4) ? b3lo[j] : b3hi[j - 4];
            t[nl][c0 + j] = fmaf(a3, of, b3) + fmaxf(fmaf(a1, yf, b1), 0.f);
        }
    }
    __syncthreads();
    const int tn = tid & 31;
    const int cq = tid >> 5;
    for (int c = cq; c < CC; c += 8)
        out[((size_t)b * CC + c) * NN + n0 + tn] = t[tn][c];
}

// ---------------------------------------------------------------------------
extern "C" void kernel_launch(void* const* d_in, const int* in_sizes, int n_in,
                              void* d_out, int out_size, void* d_ws, size_t ws_size,
                              hipStream_t stream) {
    const float* x     = (const float*)d_in[0];
    const int*   ei    = (const int*)d_in[1];
    const float* w_mr  = (const float*)d_in[2];
    const float* b_mr  = (const float*)d_in[3];
    const float* g_mr  = (const float*)d_in[4];
    const float* be_mr = (const float*)d_in[5];
    const float* w1    = (const float*)d_in[6];
    const float* b1    = (const float*)d_in[7];
    const float* g1    = (const float*)d_in[8];
    const float* be1   = (const float*)d_in[9];
    const float* w2    = (const float*)d_in[10];
    const float* b2    = (const float*)d_in[11];
    const float* g2    = (const float*)d_in[12];
    const float* be2   = (const float*)d_in[13];
    float* out = (float*)d_out;

    // workspace layout (bytes); partials live in regions dead at their time:
    //   part1 -> hF region, part2 -> oF region, part3 -> featF region
    char* ws = (char*)d_ws;
    unsigned short* xT    = (unsigned short*)(ws + 0);           // 16 MB
    unsigned short* featF = (unsigned short*)(ws + 16777216);    // 32 MB frag
    unsigned short* yF    = (unsigned short*)(ws + 50331648);    // 16 MB frag
    unsigned short* hF    = (unsigned short*)(ws + 67108864);    // 64 MB frag
    unsigned short* oF    = (unsigned short*)(ws + 134217728);   // 16 MB frag
    unsigned short* wmrF  = (unsigned short*)(ws + 150994944);   // 64 KB frag
    unsigned short* w1F   = (unsigned short*)(ws + 151060480);   // 128 KB frag
    unsigned short* w2F   = (unsigned short*)(ws + 151191552);   // 128 KB frag
    float* act1  = (float*)(ws + 151322624);                     // 2*128
    float* act2  = (float*)(ws + 151323648);                     // 2*512
    float* act3  = (float*)(ws + 151327744);                     // 2*128
    float* part1 = (float*)(ws + 67108864);                      // 1 MB (in hF)
    float* part2 = (float*)(ws + 134217728);                     // 4 MB (in oF)
    float* part3 = (float*)(ws + 16777216);                      // 1 MB (in featF)

    const float invP = 1.0f / (float)PP;

    transpose_wconv_kernel<<<dim3(NN / 32 + 80, BB), 256, 0, stream>>>(
        x, xT, w_mr, w1, w2, wmrF, w1F, w2F);
    gather_kernel<<<PP / 16, 256, 0, stream>>>(xT, ei, featF);

    // GEMM1: feat[P,256] @ w_mr^T -> y[P,128]
    sgemm2_kernel<TWO_C, CC, CC, false><<<dim3(PP / 64, 1), 256, 0, stream>>>(
        featF, wmrF, b_mr, act1, yF, part1);
    reduce_kernel<CC, PP / 64><<<CC, 256, 0, stream>>>(
        part1, g_mr, be_mr, act1, CC, invP);

    // GEMM2: relu(bn1(y))[P,128] @ w1^T -> h[P,512]   (grid.y=2: 256-ch slices)
    sgemm2_kernel<CC, 256, HH, true><<<dim3(PP / 64, 2), 256, 0, stream>>>(
        yF, w1F, b1, act1, hF, part2);
    reduce_kernel<256, PP / 64><<<HH, 256, 0, stream>>>(
        part2, g1, be1, act2, HH, invP);

    // GEMM3: relu(bn2(h))[P,512] @ w2^T -> o[P,128]  (2-chunk K staging)
    sgemm3_kernel<<<PP / 64, 256, 0, stream>>>(hF, w2F, b2, act2, oF, part3);
    reduce_kernel<CC, PP / 64><<<CC, 256, 0, stream>>>(
        part3, g2, be2, act3, CC, invP);

    // out = bn3(o) + relu(bn1(y)), back to [B,C,N]
    final_kernel<<<PP / 32, 256, 0, stream>>>(yF, oF, act1, act3, out);
}